// Round 2
// baseline (353.768 us; speedup 1.0000x reference)
//
#include <hip/hip_runtime.h>
#include <hip/hip_fp16.h>

typedef __attribute__((ext_vector_type(4)))  int   i32x4;
typedef __attribute__((ext_vector_type(16))) int   i32x16;

#define ALPHA 32
#define BM 256
#define BN 128
#define BK 128

// ---------------- kernel A: top-32 of |act_max| + keep-bitmask ----------------
__global__ __launch_bounds__(256) void topk_kernel(const float* __restrict__ act_max,
                                                   int* __restrict__ idx_out,
                                                   unsigned* __restrict__ tbits,
                                                   int K) {
  __shared__ float v[4096];
  __shared__ float rv[4];
  __shared__ int   ri[4];
  __shared__ unsigned bits[128];
  const int t = threadIdx.x;
  for (int i = t; i < K; i += 256) v[i] = fabsf(act_max[i]);
  for (int i = t; i < K / 32; i += 256) bits[i] = 0xFFFFFFFFu;
  __syncthreads();
  for (int sel = 0; sel < ALPHA; ++sel) {
    float bv = -1.f; int bi = 0;
    for (int i = t; i < K; i += 256) {
      float x = v[i];
      if (x > bv) { bv = x; bi = i; }   // ascending scan: strict > keeps lowest index
    }
    for (int m = 1; m < 64; m <<= 1) {
      float ov = __shfl_xor(bv, m);
      int   oi = __shfl_xor(bi, m);
      if (ov > bv || (ov == bv && oi < bi)) { bv = ov; bi = oi; }
    }
    if ((t & 63) == 0) { rv[t >> 6] = bv; ri[t >> 6] = bi; }
    __syncthreads();
    if (t == 0) {
      for (int u = 1; u < 4; ++u)
        if (rv[u] > bv || (rv[u] == bv && ri[u] < bi)) { bv = rv[u]; bi = ri[u]; }
      idx_out[sel] = bi;
      v[bi] = -2.f;                         // remove from candidates
      bits[bi >> 5] &= ~(1u << (bi & 31));  // t = 0 at outlier
    }
    __syncthreads();
  }
  for (int i = t; i < K / 32; i += 256) tbits[i] = bits[i];
}

// ------------- kernel B/C: per-row masked int8 quantization + gather -------------
// src [R][K] fp32 -> q [R][K] i8, smax [R] fp16, unq [ALPHA][R] fp32 (outlier cols, raw)
__global__ __launch_bounds__(256) void quant_rows_kernel(
    const float* __restrict__ src, const unsigned* __restrict__ tbits,
    const int* __restrict__ idx, signed char* __restrict__ q,
    _Float16* __restrict__ smax, float* __restrict__ unq, int K, int R) {
  __shared__ unsigned bits[128];
  __shared__ float red[4];
  const int t = threadIdx.x;
  const int r = blockIdx.x;
  for (int i = t; i < K / 32; i += 256) bits[i] = tbits[i];
  __syncthreads();
  const float4* srow = (const float4*)(src + (size_t)r * K);
  float4 vals[4];
  float am = 0.f;
#pragma unroll
  for (int i = 0; i < 4; ++i) {
    int p = i * 256 + t;
    float4 v = srow[p];
    int k0 = p << 2;
    unsigned b = bits[k0 >> 5] >> (k0 & 31);
    if (!(b & 1u)) v.x = 0.f;
    if (!(b & 2u)) v.y = 0.f;
    if (!(b & 4u)) v.z = 0.f;
    if (!(b & 8u)) v.w = 0.f;
    vals[i] = v;
    am = fmaxf(am, fmaxf(fmaxf(fabsf(v.x), fabsf(v.y)), fmaxf(fabsf(v.z), fabsf(v.w))));
  }
#pragma unroll
  for (int m = 1; m < 64; m <<= 1) am = fmaxf(am, __shfl_xor(am, m));
  if ((t & 63) == 0) red[t >> 6] = am;
  __syncthreads();
  am = fmaxf(fmaxf(red[0], red[1]), fmaxf(red[2], red[3]));
  const _Float16 sh = (_Float16)(am / 127.0f);   // RTN to fp16, like astype(float16)
  const float s = (float)sh;
  if (t == 0) smax[r] = sh;
  char4* qrow = (char4*)(q + (size_t)r * K);
#pragma unroll
  for (int i = 0; i < 4; ++i) {
    int p = i * 256 + t;
    float4 v = vals[i];
    char4 c;
    c.x = (signed char)(v.x / s);   // true fp32 division + trunc-toward-zero = astype(int8)
    c.y = (signed char)(v.y / s);
    c.z = (signed char)(v.z / s);
    c.w = (signed char)(v.w / s);
    qrow[p] = c;
  }
  if (t < ALPHA) unq[(size_t)t * R + r] = src[(size_t)r * K + idx[t]];
}

// ---------------- kernel D: i8 GEMM + fused scale/outlier/bias epilogue ----------------
// LDS layout (16B-slot granularity), chosen so BOTH the DMA write and every
// MFMA fragment read are lane-linear (base + 16*lane) => bank-conflict-free:
//   addr(row,chunk) = (row>>5)<<12 | (chunk>>1)<<10 | (chunk&1)<<9 | (row&31)<<4
// The inverse permutation is applied to the *global* source address (rule 21).
__device__ __forceinline__ void gld_lds16(const signed char* g, signed char* l) {
  __builtin_amdgcn_global_load_lds(
      (const __attribute__((address_space(1))) void*)g,
      (__attribute__((address_space(3))) void*)l, 16, 0, 0);
}

__global__ __launch_bounds__(256, 3) void gemm_kernel(
    const signed char* __restrict__ xq, const signed char* __restrict__ wq,
    const _Float16* __restrict__ xmax, const _Float16* __restrict__ wmax,
    const float* __restrict__ xuf,   // [ALPHA][M]
    const float* __restrict__ wuf,   // [ALPHA][N]
    const float* __restrict__ bias,  // [N]
    float* __restrict__ out, int M, int N, int K) {
  __shared__ union {
    struct { signed char A[BM * BK]; signed char B[BN * BK]; } g;   // 48 KB
    struct { float xu[ALPHA * BM]; float wu[ALPHA * BN]; } e;       // 48 KB
  } sm;
  __shared__ _Float16 xmh[BM];
  __shared__ _Float16 wmh[BN];
  __shared__ float    bl[BN];

  const int t = threadIdx.x;
  // XCD-aware swizzle: 1024 blocks, 8 XCDs -> each XCD owns 4 consecutive bx
  // (2 MB of B panels resident in its private L2) and sweeps all by.
  const int bid = blockIdx.y * gridDim.x + blockIdx.x;
  const int xcd = bid & 7, loc = bid >> 3;
  const int bxi = xcd * 4 + (loc & 3);
  const int byi = loc >> 2;
  const int bm0 = byi * BM;
  const int bn0 = bxi * BN;
  const int lane = t & 63, w = t >> 6;
  const int wm = w >> 1, wn = w & 1;       // 2x2 waves, wave tile 128x64
  const int hi = lane >> 5, l31 = lane & 31;

  i32x16 acc[4][2] = {};

  // staging: lane t, issue i fetches global (row = 32i + (t&31), chunk = (t>>5&1)+2*(t>>6&3))
  // and the DMA writes it linearly at LDS slot i*256+t.
  const int r31 = t & 31;
  const int chnk = ((t >> 5) & 1) + 2 * ((t >> 6) & 3);
  const signed char* aSrc = xq + (size_t)(bm0 + r31) * K + chnk * 16;
  const signed char* bSrc = wq + (size_t)(bn0 + r31) * K + chnk * 16;
  signed char* aDst = sm.g.A + t * 16;
  signed char* bDst = sm.g.B + t * 16;

  for (int k0 = 0; k0 < K; k0 += BK) {
    __syncthreads();
#pragma unroll
    for (int i = 0; i < 8; ++i) gld_lds16(aSrc + (size_t)i * 32 * K + k0, aDst + i * 4096);
#pragma unroll
    for (int i = 0; i < 4; ++i) gld_lds16(bSrc + (size_t)i * 32 * K + k0, bDst + i * 4096);
    __syncthreads();
    // fragment reads: af[mi] at A + 16*lane + 1024*ks + 4096*(wm*4+mi)  (lane-linear)
    const signed char* aRd = sm.g.A + 16 * lane + 4096 * (wm * 4);
    const signed char* bRd = sm.g.B + 16 * lane + 4096 * (wn * 2);
#pragma unroll
    for (int ks = 0; ks < 4; ++ks) {
      i32x4 af[4], bf[2];
#pragma unroll
      for (int mi = 0; mi < 4; ++mi)
        af[mi] = *(const i32x4*)(aRd + mi * 4096 + ks * 1024);
#pragma unroll
      for (int ni = 0; ni < 2; ++ni)
        bf[ni] = *(const i32x4*)(bRd + ni * 4096 + ks * 1024);
#pragma unroll
      for (int mi = 0; mi < 4; ++mi)
#pragma unroll
        for (int ni = 0; ni < 2; ++ni)
          acc[mi][ni] = __builtin_amdgcn_mfma_i32_32x32x32_i8(af[mi], bf[ni], acc[mi][ni], 0, 0, 0);
    }
  }

  __syncthreads();
  // ---- epilogue staging (reuses GEMM LDS) ----
  {
    const float4* xs = (const float4*)xuf;
    float4* xl = (float4*)sm.e.xu;
#pragma unroll
    for (int i = 0; i < 8; ++i) {   // 2048 float4
      int p = i * 256 + t;
      int j = p >> 6, r4 = p & 63;
      xl[p] = xs[(size_t)j * (M >> 2) + (bm0 >> 2) + r4];
    }
    const float4* wsrc = (const float4*)wuf;
    float4* wl = (float4*)sm.e.wu;
#pragma unroll
    for (int i = 0; i < 4; ++i) {   // 1024 float4
      int p = i * 256 + t;
      int j = p >> 5, r4 = p & 31;
      wl[p] = wsrc[(size_t)j * (N >> 2) + (bn0 >> 2) + r4];
    }
    if (t < BM / 2) ((unsigned*)xmh)[t] = ((const unsigned*)(xmax + bm0))[t];
    if (t < BN / 2) ((unsigned*)wmh)[t] = ((const unsigned*)(wmax + bn0))[t];
    if (t < BN / 4) ((float4*)bl)[t] = ((const float4*)(bias + bn0))[t];
  }
  __syncthreads();

  const int c0 = wn * 64 + l31;   // column (within tile) for ni=0; ni=1 is +32
  const _Float16 wh0 = wmh[c0], wh1 = wmh[c0 + 32];
  const float bv0 = bl[c0], bv1 = bl[c0 + 32];
  const float* xul = sm.e.xu;     // [ALPHA][BM]
  const float* wul = sm.e.wu;     // [ALPHA][BN]

#pragma unroll
  for (int mi = 0; mi < 4; ++mi) {
    const int rbase = wm * 128 + mi * 32 + 4 * hi;   // + (r&3) + 8*(r>>2)
    float f0[16], f1[16];
#pragma unroll
    for (int r = 0; r < 16; ++r) {
      int row = rbase + (r & 3) + 8 * (r >> 2);
      _Float16 xh = xmh[row];
      float mx0 = (float)(_Float16)(xh * wh0);   // fp16 multiply (subnormal-correct) like ref
      float mx1 = (float)(_Float16)(xh * wh1);
      f0[r] = (float)acc[mi][0][r] * mx0 + bv0;
      f1[r] = (float)acc[mi][1][r] * mx1 + bv1;
    }
#pragma unroll 4
    for (int j = 0; j < ALPHA; ++j) {            // rank-32 fp32 outlier update
      const float4* xrow4 = (const float4*)(xul + j * BM + rbase);
      float wv0 = wul[j * BN + c0];
      float wv1 = wul[j * BN + c0 + 32];
#pragma unroll
      for (int gq = 0; gq < 4; ++gq) {
        float4 xv = xrow4[gq * 2];               // rows rbase + 8*gq .. +3
        f0[gq * 4 + 0] += xv.x * wv0;  f1[gq * 4 + 0] += xv.x * wv1;
        f0[gq * 4 + 1] += xv.y * wv0;  f1[gq * 4 + 1] += xv.y * wv1;
        f0[gq * 4 + 2] += xv.z * wv0;  f1[gq * 4 + 2] += xv.z * wv1;
        f0[gq * 4 + 3] += xv.w * wv0;  f1[gq * 4 + 3] += xv.w * wv1;
      }
    }
#pragma unroll
    for (int r = 0; r < 16; ++r) {
      int row = bm0 + rbase + (r & 3) + 8 * (r >> 2);
      size_t o = (size_t)row * N + bn0;
      out[o + c0] = f0[r];
      out[o + c0 + 32] = f1[r];
    }
  }
}

// ---------------- launch ----------------
extern "C" void kernel_launch(void* const* d_in, const int* in_sizes, int n_in,
                              void* d_out, int out_size, void* d_ws, size_t ws_size,
                              hipStream_t stream) {
  const float* x       = (const float*)d_in[0];
  const float* W       = (const float*)d_in[1];
  const float* bias    = (const float*)d_in[2];
  const float* act_max = (const float*)d_in[3];
  const int K = in_sizes[3];            // 4096
  const int N = in_sizes[1] / K;        // 4096
  const int M = in_sizes[0] / K;        // 8192
  float* out = (float*)d_out;

  char* ws = (char*)d_ws;
  size_t off = 0;
  auto take = [&](size_t b) { char* p = ws + off; off += (b + 255) & ~(size_t)255; return p; };
  signed char* wq  = (signed char*)take((size_t)N * K);
  signed char* xq  = (signed char*)take((size_t)M * K);
  _Float16* wmax   = (_Float16*)take((size_t)N * 2);
  _Float16* xmax   = (_Float16*)take((size_t)M * 2);
  float* wuf       = (float*)take((size_t)ALPHA * N * 4);
  float* xuf       = (float*)take((size_t)ALPHA * M * 4);
  int* idx         = (int*)take(ALPHA * 4);
  unsigned* tbits  = (unsigned*)take((size_t)(K / 32) * 4);

  topk_kernel<<<1, 256, 0, stream>>>(act_max, idx, tbits, K);
  quant_rows_kernel<<<N, 256, 0, stream>>>(W, tbits, idx, wq, wmax, wuf, K, N);
  quant_rows_kernel<<<M, 256, 0, stream>>>(x, tbits, idx, xq, xmax, xuf, K, M);
  dim3 grid(N / BN, M / BM);
  gemm_kernel<<<grid, 256, 0, stream>>>(xq, wq, xmax, wmax, xuf, wuf, bias, out, M, N, K);
}

// Round 3
// 311.890 us; speedup vs baseline: 1.1343x; 1.1343x over previous
//
#include <hip/hip_runtime.h>
#include <hip/hip_fp16.h>

typedef __attribute__((ext_vector_type(4)))  int   i32x4;
typedef __attribute__((ext_vector_type(16))) int   i32x16;

#define ALPHA 32
#define BM 256
#define BN 128
#define BK 128

// Tiled int8 workspace layout (matches GEMM LDS exactly):
//   addr(row, k) = (row>>5)*(32*K) + (k>>4)*512 + (row&31)*16 + (k&15)
// i.e. panels of 32 rows; within a panel, 16B k-chunks are row-interleaved.

// ---------------- kernel A: top-32 of |act_max| + keep-bitmask ----------------
__global__ __launch_bounds__(256) void topk_kernel(const float* __restrict__ act_max,
                                                   int* __restrict__ idx_out,
                                                   unsigned* __restrict__ tbits,
                                                   int K) {
  __shared__ float v[4096];
  __shared__ float rv[4];
  __shared__ int   ri[4];
  __shared__ unsigned bits[128];
  const int t = threadIdx.x;
  for (int i = t; i < K; i += 256) v[i] = fabsf(act_max[i]);
  for (int i = t; i < K / 32; i += 256) bits[i] = 0xFFFFFFFFu;
  __syncthreads();
  for (int sel = 0; sel < ALPHA; ++sel) {
    float bv = -1.f; int bi = 0;
    for (int i = t; i < K; i += 256) {
      float x = v[i];
      if (x > bv) { bv = x; bi = i; }   // ascending scan: strict > keeps lowest index
    }
    for (int m = 1; m < 64; m <<= 1) {
      float ov = __shfl_xor(bv, m);
      int   oi = __shfl_xor(bi, m);
      if (ov > bv || (ov == bv && oi < bi)) { bv = ov; bi = oi; }
    }
    if ((t & 63) == 0) { rv[t >> 6] = bv; ri[t >> 6] = bi; }
    __syncthreads();
    if (t == 0) {
      for (int u = 1; u < 4; ++u)
        if (rv[u] > bv || (rv[u] == bv && ri[u] < bi)) { bv = rv[u]; bi = ri[u]; }
      idx_out[sel] = bi;
      v[bi] = -2.f;                         // remove from candidates
      bits[bi >> 5] &= ~(1u << (bi & 31));  // t = 0 at outlier
    }
    __syncthreads();
  }
  for (int i = t; i < K / 32; i += 256) tbits[i] = bits[i];
}

// ------------- kernel B/C: per-row masked int8 quantization + gather -------------
// src [R][K] fp32 -> q (tiled layout above) i8, smax [R] fp16, unq [ALPHA][R] fp32.
// Thread t owns k in [16t, 16t+16): 4 stride-4 float4 reads, one 16B tiled store.
__global__ __launch_bounds__(256) void quant_rows_kernel(
    const float* __restrict__ src, const unsigned* __restrict__ tbits,
    const int* __restrict__ idx, signed char* __restrict__ q,
    _Float16* __restrict__ smax, float* __restrict__ unq, int K, int R) {
  __shared__ unsigned bits[128];
  __shared__ float red[4];
  const int t = threadIdx.x;
  const int r = blockIdx.x;
  for (int i = t; i < K / 32; i += 256) bits[i] = tbits[i];
  __syncthreads();
  const float4* srow = (const float4*)(src + (size_t)r * K);
  float4 vals[4];
  float am = 0.f;
#pragma unroll
  for (int j = 0; j < 4; ++j) {
    int p = 4 * t + j;                 // k0 = 4p = 16t + 4j
    float4 v = srow[p];
    int k0 = p << 2;
    unsigned b = bits[k0 >> 5] >> (k0 & 31);
    if (!(b & 1u)) v.x = 0.f;
    if (!(b & 2u)) v.y = 0.f;
    if (!(b & 4u)) v.z = 0.f;
    if (!(b & 8u)) v.w = 0.f;
    vals[j] = v;
    am = fmaxf(am, fmaxf(fmaxf(fabsf(v.x), fabsf(v.y)), fmaxf(fabsf(v.z), fabsf(v.w))));
  }
#pragma unroll
  for (int m = 1; m < 64; m <<= 1) am = fmaxf(am, __shfl_xor(am, m));
  if ((t & 63) == 0) red[t >> 6] = am;
  __syncthreads();
  am = fmaxf(fmaxf(red[0], red[1]), fmaxf(red[2], red[3]));
  const _Float16 sh = (_Float16)(am / 127.0f);   // RTN to fp16, like astype(float16)
  const float s = (float)sh;
  if (t == 0) smax[r] = sh;
  // quantize 16 consecutive bytes, single tiled 16B store (chunk index == t)
  union { signed char c[16]; int4 v; } o;
#pragma unroll
  for (int j = 0; j < 4; ++j) {
    float4 v = vals[j];
    o.c[4 * j + 0] = (signed char)(v.x / s);   // fp32 divide + trunc = astype(int8)
    o.c[4 * j + 1] = (signed char)(v.y / s);
    o.c[4 * j + 2] = (signed char)(v.z / s);
    o.c[4 * j + 3] = (signed char)(v.w / s);
  }
  *(int4*)(q + (size_t)(r >> 5) * 32 * K + (size_t)t * 512 + (r & 31) * 16) = o.v;
  if (t < ALPHA) unq[(size_t)t * R + r] = src[(size_t)r * K + idx[t]];
}

// ---------------- kernel D: i8 GEMM + fused scale/outlier/bias epilogue ----------------
// Staging: issue i copies one contiguous 4KB global block (panel i, 8 chunks at k0)
// to LDS linearly (slot t*16). Fragment reads are lane-linear -> 0 bank conflicts.
__device__ __forceinline__ void gld_lds16(const signed char* g, signed char* l) {
  __builtin_amdgcn_global_load_lds(
      (const __attribute__((address_space(1))) void*)g,
      (__attribute__((address_space(3))) void*)l, 16, 0, 0);
}

__global__ __launch_bounds__(256, 2) void gemm_kernel(
    const signed char* __restrict__ xq, const signed char* __restrict__ wq,
    const _Float16* __restrict__ xmax, const _Float16* __restrict__ wmax,
    const float* __restrict__ xuf,   // [ALPHA][M]
    const float* __restrict__ wuf,   // [ALPHA][N]
    const float* __restrict__ bias,  // [N]
    float* __restrict__ out, int M, int N, int K) {
  __shared__ union {
    struct { signed char A[BM * BK]; signed char B[BN * BK]; } g;   // 48 KB
    struct { float xu[ALPHA * BM]; float wu[ALPHA * BN]; } e;       // 48 KB
  } sm;
  __shared__ _Float16 xmh[BM];
  __shared__ _Float16 wmh[BN];
  __shared__ float    bl[BN];

  const int t = threadIdx.x;
  // XCD-aware swizzle: 1024 blocks, 8 XCDs -> each XCD owns 4 consecutive bx
  // (2 MB of B panels resident in its private L2) and sweeps all by.
  const int bid = blockIdx.y * gridDim.x + blockIdx.x;
  const int xcd = bid & 7, loc = bid >> 3;
  const int bxi = xcd * 4 + (loc & 3);
  const int byi = loc >> 2;
  const int bm0 = byi * BM;
  const int bn0 = bxi * BN;
  const int lane = t & 63, w = t >> 6;
  const int wm = w >> 1, wn = w & 1;       // 2x2 waves, wave tile 128x64
  const int hi = lane >> 5, l31 = lane & 31;

  i32x16 acc[4][2] = {};

  // tiled-layout staging bases: contiguous 4KB per issue
  const signed char* aSrc = xq + (size_t)bm0 * K + 16 * t;
  const signed char* bSrc = wq + (size_t)bn0 * K + 16 * t;
  signed char* aDst = sm.g.A + t * 16;
  signed char* bDst = sm.g.B + t * 16;

  for (int k0 = 0; k0 < K; k0 += BK) {
    __syncthreads();
    const size_t koff = (size_t)k0 * 32;   // (k0>>4)*512
#pragma unroll
    for (int i = 0; i < 8; ++i) gld_lds16(aSrc + (size_t)i * 32 * K + koff, aDst + i * 4096);
#pragma unroll
    for (int i = 0; i < 4; ++i) gld_lds16(bSrc + (size_t)i * 32 * K + koff, bDst + i * 4096);
    __syncthreads();
    // fragment reads: af[mi] at A + 16*lane + 1024*ks + 4096*(wm*4+mi)  (lane-linear)
    const signed char* aRd = sm.g.A + 16 * lane + 4096 * (wm * 4);
    const signed char* bRd = sm.g.B + 16 * lane + 4096 * (wn * 2);
#pragma unroll
    for (int ks = 0; ks < 4; ++ks) {
      i32x4 af[4], bf[2];
#pragma unroll
      for (int mi = 0; mi < 4; ++mi)
        af[mi] = *(const i32x4*)(aRd + mi * 4096 + ks * 1024);
#pragma unroll
      for (int ni = 0; ni < 2; ++ni)
        bf[ni] = *(const i32x4*)(bRd + ni * 4096 + ks * 1024);
#pragma unroll
      for (int mi = 0; mi < 4; ++mi)
#pragma unroll
        for (int ni = 0; ni < 2; ++ni)
          acc[mi][ni] = __builtin_amdgcn_mfma_i32_32x32x32_i8(af[mi], bf[ni], acc[mi][ni], 0, 0, 0);
    }
  }

  __syncthreads();
  // ---- epilogue staging (reuses GEMM LDS) ----
  {
    const float4* xs = (const float4*)xuf;
    float4* xl = (float4*)sm.e.xu;
#pragma unroll
    for (int i = 0; i < 8; ++i) {   // 2048 float4
      int p = i * 256 + t;
      int j = p >> 6, r4 = p & 63;
      xl[p] = xs[(size_t)j * (M >> 2) + (bm0 >> 2) + r4];
    }
    const float4* wsrc = (const float4*)wuf;
    float4* wl = (float4*)sm.e.wu;
#pragma unroll
    for (int i = 0; i < 4; ++i) {   // 1024 float4
      int p = i * 256 + t;
      int j = p >> 5, r4 = p & 31;
      wl[p] = wsrc[(size_t)j * (N >> 2) + (bn0 >> 2) + r4];
    }
    if (t < BM / 2) ((unsigned*)xmh)[t] = ((const unsigned*)(xmax + bm0))[t];
    if (t < BN / 2) ((unsigned*)wmh)[t] = ((const unsigned*)(wmax + bn0))[t];
    if (t < BN / 4) ((float4*)bl)[t] = ((const float4*)(bias + bn0))[t];
  }
  __syncthreads();

  const int c0 = wn * 64 + l31;   // column (within tile) for ni=0; ni=1 is +32
  const _Float16 wh0 = wmh[c0], wh1 = wmh[c0 + 32];
  const float bv0 = bl[c0], bv1 = bl[c0 + 32];
  const float* xul = sm.e.xu;     // [ALPHA][BM]
  const float* wul = sm.e.wu;     // [ALPHA][BN]

#pragma unroll
  for (int mi = 0; mi < 4; ++mi) {
    const int rbase = wm * 128 + mi * 32 + 4 * hi;   // + (r&3) + 8*(r>>2)
    float f0[16], f1[16];
#pragma unroll
    for (int r = 0; r < 16; ++r) {
      int row = rbase + (r & 3) + 8 * (r >> 2);
      _Float16 xh = xmh[row];
      float mx0 = (float)(_Float16)(xh * wh0);   // fp16 multiply (subnormal-correct) like ref
      float mx1 = (float)(_Float16)(xh * wh1);
      f0[r] = (float)acc[mi][0][r] * mx0 + bv0;
      f1[r] = (float)acc[mi][1][r] * mx1 + bv1;
    }
#pragma unroll 4
    for (int j = 0; j < ALPHA; ++j) {            // rank-32 fp32 outlier update
      const float4* xrow4 = (const float4*)(xul + j * BM + rbase);
      float wv0 = wul[j * BN + c0];
      float wv1 = wul[j * BN + c0 + 32];
#pragma unroll
      for (int gq = 0; gq < 4; ++gq) {
        float4 xv = xrow4[gq * 2];               // rows rbase + 8*gq .. +3
        f0[gq * 4 + 0] += xv.x * wv0;  f1[gq * 4 + 0] += xv.x * wv1;
        f0[gq * 4 + 1] += xv.y * wv0;  f1[gq * 4 + 1] += xv.y * wv1;
        f0[gq * 4 + 2] += xv.z * wv0;  f1[gq * 4 + 2] += xv.z * wv1;
        f0[gq * 4 + 3] += xv.w * wv0;  f1[gq * 4 + 3] += xv.w * wv1;
      }
    }
#pragma unroll
    for (int r = 0; r < 16; ++r) {
      int row = bm0 + rbase + (r & 3) + 8 * (r >> 2);
      size_t o = (size_t)row * N + bn0;
      out[o + c0] = f0[r];
      out[o + c0 + 32] = f1[r];
    }
  }
}

// ---------------- launch ----------------
extern "C" void kernel_launch(void* const* d_in, const int* in_sizes, int n_in,
                              void* d_out, int out_size, void* d_ws, size_t ws_size,
                              hipStream_t stream) {
  const float* x       = (const float*)d_in[0];
  const float* W       = (const float*)d_in[1];
  const float* bias    = (const float*)d_in[2];
  const float* act_max = (const float*)d_in[3];
  const int K = in_sizes[3];            // 4096
  const int N = in_sizes[1] / K;        // 4096
  const int M = in_sizes[0] / K;        // 8192
  float* out = (float*)d_out;

  char* ws = (char*)d_ws;
  size_t off = 0;
  auto take = [&](size_t b) { char* p = ws + off; off += (b + 255) & ~(size_t)255; return p; };
  signed char* wq  = (signed char*)take((size_t)N * K);
  signed char* xq  = (signed char*)take((size_t)M * K);
  _Float16* wmax   = (_Float16*)take((size_t)N * 2);
  _Float16* xmax   = (_Float16*)take((size_t)M * 2);
  float* wuf       = (float*)take((size_t)ALPHA * N * 4);
  float* xuf       = (float*)take((size_t)ALPHA * M * 4);
  int* idx         = (int*)take(ALPHA * 4);
  unsigned* tbits  = (unsigned*)take((size_t)(K / 32) * 4);

  topk_kernel<<<1, 256, 0, stream>>>(act_max, idx, tbits, K);
  quant_rows_kernel<<<N, 256, 0, stream>>>(W, tbits, idx, wq, wmax, wuf, K, N);
  quant_rows_kernel<<<M, 256, 0, stream>>>(x, tbits, idx, xq, xmax, xuf, K, M);
  dim3 grid(N / BN, M / BM);
  gemm_kernel<<<grid, 256, 0, stream>>>(xq, wq, xmax, wmax, xuf, wuf, bias, out, M, N, K);
}